// Round 1
// baseline (107814.551 us; speedup 1.0000x reference)
//
#include <hip/hip_runtime.h>

// LSTMGapFiller: 2x bidir ctx LSTM (H=256) -> combined init -> 2-layer decoder
// LSTM (HG=512) with argmax token feedback, T=256 (target_length fixed by setup).
// Round 0: correctness-first fp32. Batch elems independent => ctx recurrences run
// whole 100-step chain per block (h,c in LDS). Decoder: 3 kernels/step for the
// two grid-wide dependencies (h0 -> layer1, h1 -> argmax -> tok).

#define L_SEQ 100
#define BATCH 1024
#define HCTX 256
#define HG 512
#define TDEC 256

__device__ __forceinline__ float sigf(float x){ return 1.0f/(1.0f+expf(-x)); }

// src[J][K] -> dst[K][J]
__global__ void transpose_k(const float* __restrict__ src, float* __restrict__ dst,
                            int J, int K){
  int idx = blockIdx.x*blockDim.x + threadIdx.x;
  if (idx < J*K){
    int j = idx / K, k = idx % K;
    dst[k*J + j] = src[idx];
  }
}

// precompute embedding projections (vocab=5):
// ectx0[d][v][j] = ctx0_b[d][j] + emb[v] . ctx0_Wih[d][j]   (j<1024)
// egen0[v][j]    = gen0_b[j]    + emb[v] . gen0_Wih[j]      (j<2048)
__global__ void embprep(const float* __restrict__ emb,
                        const float* __restrict__ c0Wih, const float* __restrict__ c0b,
                        const float* __restrict__ g0Wih, const float* __restrict__ g0b,
                        float* __restrict__ ectx0, float* __restrict__ egen0){
  int idx = blockIdx.x*blockDim.x + threadIdx.x;
  if (idx < 2*5*1024){
    int d = idx / 5120;
    int v = (idx / 1024) % 5;
    int j = idx % 1024;
    const float* w = c0Wih + ((size_t)d*1024 + j)*64;
    const float* e = emb + v*64;
    float s = c0b[d*1024 + j];
    #pragma unroll
    for (int k=0;k<64;k++) s += e[k]*w[k];
    ectx0[idx] = s;
  } else if (idx < 2*5*1024 + 5*2048){
    int i2 = idx - 10240;
    int v = i2 / 2048;
    int j = i2 % 2048;
    const float* w = g0Wih + (size_t)j*64;
    const float* e = emb + v*64;
    float s = g0b[j];
    #pragma unroll
    for (int k=0;k<64;k++) s += e[k]*w[k];
    egen0[i2] = s;
  }
}

// ctx layer 0: grid (128 batch-groups, 2 dirs), block 256 (thread = hidden unit u).
// Each block owns 8 batch elems, loops all 100 steps; h,c live in LDS.
// Writes y0[t][b][dir*256+u]  (y0: [100][1024][512], original time index).
__global__ void ctx_l0(const int* __restrict__ toks,
                       const float* __restrict__ ectx0,
                       const float* __restrict__ whhT,
                       float* __restrict__ y0){
  const int dir = blockIdx.y;
  const int e0 = blockIdx.x * 8;
  const int u = threadIdx.x;
  __shared__ float hs[8][256];
  __shared__ float cs[8][256];
  #pragma unroll
  for (int e=0;e<8;e++){ hs[e][u]=0.f; cs[e][u]=0.f; }
  __syncthreads();
  const float* wbase = whhT + (size_t)dir*256*1024;
  for (int s=0;s<L_SEQ;s++){
    const int t = dir ? (L_SEQ-1-s) : s;
    float acc[8][4];
    #pragma unroll
    for (int e=0;e<8;e++){
      int tk = toks[(e0+e)*L_SEQ + t];
      const float* ep = ectx0 + ((size_t)dir*5 + tk)*1024 + u;
      acc[e][0]=ep[0]; acc[e][1]=ep[256]; acc[e][2]=ep[512]; acc[e][3]=ep[768];
    }
    for (int k=0;k<256;k++){
      const float* w = wbase + k*1024 + u;
      float w0=w[0], w1=w[256], w2=w[512], w3=w[768];
      #pragma unroll
      for (int e=0;e<8;e++){
        float hv = hs[e][k];
        acc[e][0] += hv*w0; acc[e][1] += hv*w1;
        acc[e][2] += hv*w2; acc[e][3] += hv*w3;
      }
    }
    __syncthreads();
    #pragma unroll
    for (int e=0;e<8;e++){
      float ig = sigf(acc[e][0]);
      float fg = sigf(acc[e][1]);
      float gg = tanhf(acc[e][2]);
      float og = sigf(acc[e][3]);
      float c = fg*cs[e][u] + ig*gg;
      float h = og*tanhf(c);
      cs[e][u]=c; hs[e][u]=h;
      y0[((size_t)t*BATCH + (e0+e))*512 + dir*256 + u] = h;
    }
    __syncthreads();
  }
}

// ctx layer 1: input x = y0[t] (512-wide). Stores h into finals at t==t_store
// (left_final: t=99 both dirs; right_final: t=0 both dirs).
__global__ void ctx_l1(const float* __restrict__ y0,
                       const float* __restrict__ wihT,
                       const float* __restrict__ whhT,
                       const float* __restrict__ bias,
                       float* __restrict__ finals, int t_store){
  const int dir = blockIdx.y;
  const int e0 = blockIdx.x * 8;
  const int u = threadIdx.x;
  __shared__ float hs[8][256];
  __shared__ float cs[8][256];
  __shared__ float xs[8][512];
  #pragma unroll
  for (int e=0;e<8;e++){ hs[e][u]=0.f; cs[e][u]=0.f; }
  __syncthreads();
  const float* wi = wihT + (size_t)dir*512*1024;
  const float* wh = whhT + (size_t)dir*256*1024;
  const float b0 = bias[dir*1024 + u];
  const float b1 = bias[dir*1024 + 256 + u];
  const float b2 = bias[dir*1024 + 512 + u];
  const float b3 = bias[dir*1024 + 768 + u];
  for (int s=0;s<L_SEQ;s++){
    const int t = dir ? (L_SEQ-1-s) : s;
    const float* xsrc = y0 + ((size_t)t*BATCH + e0)*512;
    for (int i=u;i<8*512;i+=256) ((float*)xs)[i] = xsrc[i];
    __syncthreads();
    float acc[8][4];
    #pragma unroll
    for (int e=0;e<8;e++){ acc[e][0]=b0; acc[e][1]=b1; acc[e][2]=b2; acc[e][3]=b3; }
    for (int k=0;k<512;k++){
      const float* w = wi + k*1024 + u;
      float w0=w[0], w1=w[256], w2=w[512], w3=w[768];
      #pragma unroll
      for (int e=0;e<8;e++){
        float xv = xs[e][k];
        acc[e][0]+=xv*w0; acc[e][1]+=xv*w1; acc[e][2]+=xv*w2; acc[e][3]+=xv*w3;
      }
    }
    for (int k=0;k<256;k++){
      const float* w = wh + k*1024 + u;
      float w0=w[0], w1=w[256], w2=w[512], w3=w[768];
      #pragma unroll
      for (int e=0;e<8;e++){
        float hv = hs[e][k];
        acc[e][0]+=hv*w0; acc[e][1]+=hv*w1; acc[e][2]+=hv*w2; acc[e][3]+=hv*w3;
      }
    }
    __syncthreads();
    #pragma unroll
    for (int e=0;e<8;e++){
      float ig = sigf(acc[e][0]);
      float fg = sigf(acc[e][1]);
      float gg = tanhf(acc[e][2]);
      float og = sigf(acc[e][3]);
      float c = fg*cs[e][u] + ig*gg;
      float h = og*tanhf(c);
      cs[e][u]=c; hs[e][u]=h;
      if (t == t_store) finals[(size_t)(e0+e)*512 + dir*256 + u] = h;
    }
    __syncthreads();
  }
}

__global__ void combine_init(const float* __restrict__ lf, const float* __restrict__ rf,
                             float* __restrict__ h0, float* __restrict__ c0,
                             float* __restrict__ h1, float* __restrict__ c1,
                             int* __restrict__ tok){
  int i = blockIdx.x*blockDim.x + threadIdx.x;
  if (i < BATCH*HG){
    float v = 0.5f*(lf[i]+rf[i]);
    h0[i]=v; h1[i]=v; c0[i]=0.f; c1[i]=0.f;
  }
  if (i < BATCH) tok[i]=0;
}

// decoder layer 0: grid (64 batch-groups, 4 unit-groups), block 256.
// Block = 16 elems x 128 units; thread = 1 unit, 8 elems, 4 gates.
// z = egen0[tok] + h_prev @ WhhT ; h double-buffered (hin/hout), c in place.
__global__ void dec_l0(const int* __restrict__ tok,
                       const float* __restrict__ egen0,
                       const float* __restrict__ whhT,
                       const float* __restrict__ hin,
                       float* __restrict__ hout,
                       float* __restrict__ cst){
  const int e0 = blockIdx.x * 16;
  const int u = blockIdx.y*128 + (threadIdx.x & 127);
  const int er = threadIdx.x >> 7;   // 0..1, wave-uniform
  __shared__ float xs[16][512];
  for (int i=threadIdx.x; i<16*512; i+=256)
    ((float*)xs)[i] = hin[(size_t)e0*512 + i];
  __syncthreads();
  float acc[8][4];
  #pragma unroll
  for (int j=0;j<8;j++){
    int el = er + j*2;
    int tk = tok[e0+el];
    const float* ep = egen0 + (size_t)tk*2048 + u;
    acc[j][0]=ep[0]; acc[j][1]=ep[512]; acc[j][2]=ep[1024]; acc[j][3]=ep[1536];
  }
  for (int k=0;k<512;k++){
    const float* w = whhT + (size_t)k*2048 + u;
    float w0=w[0], w1=w[512], w2=w[1024], w3=w[1536];
    #pragma unroll
    for (int j=0;j<8;j++){
      float hv = xs[er + j*2][k];
      acc[j][0]+=hv*w0; acc[j][1]+=hv*w1; acc[j][2]+=hv*w2; acc[j][3]+=hv*w3;
    }
  }
  #pragma unroll
  for (int j=0;j<8;j++){
    int e = e0 + er + j*2;
    size_t idx = (size_t)e*512 + u;
    float ig = sigf(acc[j][0]);
    float fg = sigf(acc[j][1]);
    float gg = tanhf(acc[j][2]);
    float og = sigf(acc[j][3]);
    float c = fg*cst[idx] + ig*gg;
    float h = og*tanhf(c);
    cst[idx]=c; hout[idx]=h;
  }
}

// decoder layer 1: z = b + x @ WihT + h_prev @ WhhT  (x = new h0)
__global__ void dec_l1(const float* __restrict__ x,
                       const float* __restrict__ wihT,
                       const float* __restrict__ whhT,
                       const float* __restrict__ bias,
                       const float* __restrict__ hin,
                       float* __restrict__ hout,
                       float* __restrict__ cst){
  const int e0 = blockIdx.x * 16;
  const int u = blockIdx.y*128 + (threadIdx.x & 127);
  const int er = threadIdx.x >> 7;
  __shared__ float xs[16][512];
  __shared__ float hsh[16][512];
  for (int i=threadIdx.x; i<16*512; i+=256){
    ((float*)xs)[i]  = x[(size_t)e0*512 + i];
    ((float*)hsh)[i] = hin[(size_t)e0*512 + i];
  }
  __syncthreads();
  float acc[8][4];
  const float b0=bias[u], b1=bias[512+u], b2=bias[1024+u], b3=bias[1536+u];
  #pragma unroll
  for (int j=0;j<8;j++){ acc[j][0]=b0; acc[j][1]=b1; acc[j][2]=b2; acc[j][3]=b3; }
  for (int k=0;k<512;k++){
    const float* w = wihT + (size_t)k*2048 + u;
    float w0=w[0], w1=w[512], w2=w[1024], w3=w[1536];
    #pragma unroll
    for (int j=0;j<8;j++){
      float xv = xs[er + j*2][k];
      acc[j][0]+=xv*w0; acc[j][1]+=xv*w1; acc[j][2]+=xv*w2; acc[j][3]+=xv*w3;
    }
  }
  for (int k=0;k<512;k++){
    const float* w = whhT + (size_t)k*2048 + u;
    float w0=w[0], w1=w[512], w2=w[1024], w3=w[1536];
    #pragma unroll
    for (int j=0;j<8;j++){
      float hv = hsh[er + j*2][k];
      acc[j][0]+=hv*w0; acc[j][1]+=hv*w1; acc[j][2]+=hv*w2; acc[j][3]+=hv*w3;
    }
  }
  #pragma unroll
  for (int j=0;j<8;j++){
    int e = e0 + er + j*2;
    size_t idx = (size_t)e*512 + u;
    float ig=sigf(acc[j][0]), fg=sigf(acc[j][1]);
    float gg=tanhf(acc[j][2]), og=sigf(acc[j][3]);
    float c = fg*cst[idx] + ig*gg;
    float h = og*tanhf(c);
    cst[idx]=c; hout[idx]=h;
  }
}

// logits + argmax: one wave per batch elem (4 waves/block, 256 blocks)
__global__ void dec_out(const float* __restrict__ h1,
                        const float* __restrict__ outW,
                        const float* __restrict__ outb,
                        float* __restrict__ out,
                        int* __restrict__ tok, int t){
  const int lane = threadIdx.x & 63;
  const int e = blockIdx.x*4 + (threadIdx.x >> 6);
  const float* h = h1 + (size_t)e*512;
  float s0=0,s1=0,s2=0,s3=0,s4=0;
  for (int k=lane;k<512;k+=64){
    float hv = h[k];
    s0 += hv*outW[k];
    s1 += hv*outW[512+k];
    s2 += hv*outW[1024+k];
    s3 += hv*outW[1536+k];
    s4 += hv*outW[2048+k];
  }
  #pragma unroll
  for (int off=32; off>0; off>>=1){
    s0 += __shfl_down(s0, off);
    s1 += __shfl_down(s1, off);
    s2 += __shfl_down(s2, off);
    s3 += __shfl_down(s3, off);
    s4 += __shfl_down(s4, off);
  }
  if (lane==0){
    float l[5] = { s0+outb[0], s1+outb[1], s2+outb[2], s3+outb[3], s4+outb[4] };
    float* op = out + ((size_t)e*TDEC + t)*5;
    float best = l[0]; int bi = 0;
    op[0] = l[0];
    #pragma unroll
    for (int v=1;v<5;v++){
      op[v] = l[v];
      if (l[v] > best){ best = l[v]; bi = v; }  // first-max, matches jnp.argmax
    }
    tok[e] = bi;
  }
}

extern "C" void kernel_launch(void* const* d_in, const int* in_sizes, int n_in,
                              void* d_out, int out_size, void* d_ws, size_t ws_size,
                              hipStream_t stream){
  (void)in_sizes; (void)n_in; (void)out_size;
  const int*   leftc    = (const int*)d_in[0];
  const int*   rightc   = (const int*)d_in[1];
  // d_in[2] = target_length (fixed 256 by setup_inputs; hardcoded as TDEC)
  const float* emb      = (const float*)d_in[3];
  const float* ctx0_Wih = (const float*)d_in[4];
  const float* ctx0_Whh = (const float*)d_in[5];
  const float* ctx0_b   = (const float*)d_in[6];
  const float* ctx1_Wih = (const float*)d_in[7];
  const float* ctx1_Whh = (const float*)d_in[8];
  const float* ctx1_b   = (const float*)d_in[9];
  const float* gen0_Wih = (const float*)d_in[10];
  const float* gen0_Whh = (const float*)d_in[11];
  const float* gen0_b   = (const float*)d_in[12];
  const float* gen1_Wih = (const float*)d_in[13];
  const float* gen1_Whh = (const float*)d_in[14];
  const float* gen1_b   = (const float*)d_in[15];
  const float* out_W    = (const float*)d_in[16];
  const float* out_b    = (const float*)d_in[17];
  float* out = (float*)d_out;

  char* p = (char*)d_ws;
  auto carve = [&](size_t nfloats)->float*{
    float* r = (float*)p;
    p += ((nfloats*sizeof(float) + 255) & ~(size_t)255);
    return r;
  };
  float* c0WhhT = carve((size_t)2*256*1024);
  float* c1WihT = carve((size_t)2*512*1024);
  float* c1WhhT = carve((size_t)2*256*1024);
  float* g0WhhT = carve((size_t)512*2048);
  float* g1WihT = carve((size_t)512*2048);
  float* g1WhhT = carve((size_t)512*2048);
  float* ectx0  = carve(2*5*1024);
  float* egen0  = carve(5*2048);
  float* leftF  = carve((size_t)BATCH*HG);
  float* rightF = carve((size_t)BATCH*HG);
  float* h0a    = carve((size_t)BATCH*HG);
  float* h0b    = carve((size_t)BATCH*HG);
  float* h1a    = carve((size_t)BATCH*HG);
  float* h1b    = carve((size_t)BATCH*HG);
  float* c0s    = carve((size_t)BATCH*HG);
  float* c1s    = carve((size_t)BATCH*HG);
  int*   tok    = (int*)carve(BATCH);
  float* y0     = carve((size_t)L_SEQ*BATCH*512);   // 210 MB, largest last
  if ((size_t)(p - (char*)d_ws) > ws_size) return;  // insufficient workspace -> loud fail

  auto T = [&](const float* s, float* d, int J, int K){
    int n = J*K;
    transpose_k<<<(n+255)/256, 256, 0, stream>>>(s, d, J, K);
  };
  T(ctx0_Whh,          c0WhhT,          1024, 256);
  T(ctx0_Whh+1024*256, c0WhhT+256*1024, 1024, 256);
  T(ctx1_Wih,          c1WihT,          1024, 512);
  T(ctx1_Wih+1024*512, c1WihT+512*1024, 1024, 512);
  T(ctx1_Whh,          c1WhhT,          1024, 256);
  T(ctx1_Whh+1024*256, c1WhhT+256*1024, 1024, 256);
  T(gen0_Whh, g0WhhT, 2048, 512);
  T(gen1_Wih, g1WihT, 2048, 512);
  T(gen1_Whh, g1WhhT, 2048, 512);
  embprep<<<(20480+255)/256, 256, 0, stream>>>(emb, ctx0_Wih, ctx0_b,
                                               gen0_Wih, gen0_b, ectx0, egen0);

  // left encode (finals at original t=99), then right (finals at t=0); y0 reused
  ctx_l0<<<dim3(128,2), 256, 0, stream>>>(leftc, ectx0, c0WhhT, y0);
  ctx_l1<<<dim3(128,2), 256, 0, stream>>>(y0, c1WihT, c1WhhT, ctx1_b, leftF, L_SEQ-1);
  ctx_l0<<<dim3(128,2), 256, 0, stream>>>(rightc, ectx0, c0WhhT, y0);
  ctx_l1<<<dim3(128,2), 256, 0, stream>>>(y0, c1WihT, c1WhhT, ctx1_b, rightF, 0);

  combine_init<<<(BATCH*HG+255)/256, 256, 0, stream>>>(leftF, rightF,
                                                       h0a, c0s, h1a, c1s, tok);

  for (int t=0;t<TDEC;t++){
    float* h0in  = (t&1)? h0b : h0a;
    float* h0out = (t&1)? h0a : h0b;
    float* h1in  = (t&1)? h1b : h1a;
    float* h1out = (t&1)? h1a : h1b;
    dec_l0<<<dim3(64,4), 256, 0, stream>>>(tok, egen0, g0WhhT, h0in, h0out, c0s);
    dec_l1<<<dim3(64,4), 256, 0, stream>>>(h0out, g1WihT, g1WhhT, gen1_b,
                                           h1in, h1out, c1s);
    dec_out<<<256, 256, 0, stream>>>(h1out, out_W, out_b, out, tok, t);
  }
}

// Round 2
// 72507.373 us; speedup vs baseline: 1.4869x; 1.4869x over previous
//
#include <hip/hip_runtime.h>

// LSTMGapFiller R1: occupancy/ILP pass. 2 waves/SIMD everywhere (was 1):
// ctx kernels -> 512-thread blocks; decoder -> 512 blocks (2/CU), 4 elems/thread
// (16 independent FMA chains/thread). dec_l1 k-loops merged over concatenated
// [WihT;WhhT]. fp32 throughout (correctness anchor).

#define L_SEQ 100
#define BATCH 1024
#define HCTX 256
#define HG 512
#define TDEC 256

__device__ __forceinline__ float sigf(float x){ return 1.0f/(1.0f+expf(-x)); }

// src[J][K] -> dst[K][J]
__global__ void transpose_k(const float* __restrict__ src, float* __restrict__ dst,
                            int J, int K){
  int idx = blockIdx.x*blockDim.x + threadIdx.x;
  if (idx < J*K){
    int j = idx / K, k = idx % K;
    dst[k*J + j] = src[idx];
  }
}

// precompute embedding projections (vocab=5):
// ectx0[d][v][j] = ctx0_b[d][j] + emb[v] . ctx0_Wih[d][j]   (j<1024)
// egen0[v][j]    = gen0_b[j]    + emb[v] . gen0_Wih[j]      (j<2048)
__global__ void embprep(const float* __restrict__ emb,
                        const float* __restrict__ c0Wih, const float* __restrict__ c0b,
                        const float* __restrict__ g0Wih, const float* __restrict__ g0b,
                        float* __restrict__ ectx0, float* __restrict__ egen0){
  int idx = blockIdx.x*blockDim.x + threadIdx.x;
  if (idx < 2*5*1024){
    int d = idx / 5120;
    int v = (idx / 1024) % 5;
    int j = idx % 1024;
    const float* w = c0Wih + ((size_t)d*1024 + j)*64;
    const float* e = emb + v*64;
    float s = c0b[d*1024 + j];
    #pragma unroll
    for (int k=0;k<64;k++) s += e[k]*w[k];
    ectx0[idx] = s;
  } else if (idx < 2*5*1024 + 5*2048){
    int i2 = idx - 10240;
    int v = i2 / 2048;
    int j = i2 % 2048;
    const float* w = g0Wih + (size_t)j*64;
    const float* e = emb + v*64;
    float s = g0b[j];
    #pragma unroll
    for (int k=0;k<64;k++) s += e[k]*w[k];
    egen0[i2] = s;
  }
}

// ctx layer 0: grid (128, 2), block 512 (u = tid&255, eh = tid>>8 owns 4 elems).
// Block owns 8 batch elems for all 100 steps; h,c in LDS.
__global__ void ctx_l0(const int* __restrict__ toks,
                       const float* __restrict__ ectx0,
                       const float* __restrict__ whhT,
                       float* __restrict__ y0){
  const int dir = blockIdx.y;
  const int e0 = blockIdx.x * 8;
  const int u = threadIdx.x & 255;
  const int eh = threadIdx.x >> 8;      // 0..1 (wave-uniform)
  __shared__ float hs[8][256];
  __shared__ float cs[8][256];
  #pragma unroll
  for (int j=0;j<4;j++){ hs[eh*4+j][u]=0.f; cs[eh*4+j][u]=0.f; }
  __syncthreads();
  const float* wbase = whhT + (size_t)dir*256*1024;
  for (int s=0;s<L_SEQ;s++){
    const int t = dir ? (L_SEQ-1-s) : s;
    float acc[4][4];
    #pragma unroll
    for (int j=0;j<4;j++){
      int e = eh*4+j;
      int tk = toks[(e0+e)*L_SEQ + t];
      const float* ep = ectx0 + ((size_t)dir*5 + tk)*1024 + u;
      acc[j][0]=ep[0]; acc[j][1]=ep[256]; acc[j][2]=ep[512]; acc[j][3]=ep[768];
    }
    for (int k=0;k<256;k++){
      const float* w = wbase + k*1024 + u;
      float w0=w[0], w1=w[256], w2=w[512], w3=w[768];
      #pragma unroll
      for (int j=0;j<4;j++){
        float hv = hs[eh*4+j][k];
        acc[j][0]+=hv*w0; acc[j][1]+=hv*w1; acc[j][2]+=hv*w2; acc[j][3]+=hv*w3;
      }
    }
    __syncthreads();
    #pragma unroll
    for (int j=0;j<4;j++){
      int e = eh*4+j;
      float ig = sigf(acc[j][0]);
      float fg = sigf(acc[j][1]);
      float gg = tanhf(acc[j][2]);
      float og = sigf(acc[j][3]);
      float c = fg*cs[e][u] + ig*gg;
      float h = og*tanhf(c);
      cs[e][u]=c; hs[e][u]=h;
      y0[((size_t)t*BATCH + (e0+e))*512 + dir*256 + u] = h;
    }
    __syncthreads();
  }
}

// ctx layer 1: input x = y0[t] (512-wide). block 512 threads as ctx_l0.
__global__ void ctx_l1(const float* __restrict__ y0,
                       const float* __restrict__ wihT,
                       const float* __restrict__ whhT,
                       const float* __restrict__ bias,
                       float* __restrict__ finals, int t_store){
  const int dir = blockIdx.y;
  const int e0 = blockIdx.x * 8;
  const int u = threadIdx.x & 255;
  const int eh = threadIdx.x >> 8;
  __shared__ float hs[8][256];
  __shared__ float cs[8][256];
  __shared__ float xs[8][512];
  #pragma unroll
  for (int j=0;j<4;j++){ hs[eh*4+j][u]=0.f; cs[eh*4+j][u]=0.f; }
  __syncthreads();
  const float* wi = wihT + (size_t)dir*512*1024;
  const float* wh = whhT + (size_t)dir*256*1024;
  const float b0 = bias[dir*1024 + u];
  const float b1 = bias[dir*1024 + 256 + u];
  const float b2 = bias[dir*1024 + 512 + u];
  const float b3 = bias[dir*1024 + 768 + u];
  for (int s=0;s<L_SEQ;s++){
    const int t = dir ? (L_SEQ-1-s) : s;
    const float* xsrc = y0 + ((size_t)t*BATCH + e0)*512;
    for (int i=threadIdx.x;i<8*512;i+=512) ((float*)xs)[i] = xsrc[i];
    __syncthreads();
    float acc[4][4];
    #pragma unroll
    for (int j=0;j<4;j++){ acc[j][0]=b0; acc[j][1]=b1; acc[j][2]=b2; acc[j][3]=b3; }
    for (int k=0;k<512;k++){
      const float* w = wi + k*1024 + u;
      float w0=w[0], w1=w[256], w2=w[512], w3=w[768];
      #pragma unroll
      for (int j=0;j<4;j++){
        float xv = xs[eh*4+j][k];
        acc[j][0]+=xv*w0; acc[j][1]+=xv*w1; acc[j][2]+=xv*w2; acc[j][3]+=xv*w3;
      }
    }
    for (int k=0;k<256;k++){
      const float* w = wh + k*1024 + u;
      float w0=w[0], w1=w[256], w2=w[512], w3=w[768];
      #pragma unroll
      for (int j=0;j<4;j++){
        float hv = hs[eh*4+j][k];
        acc[j][0]+=hv*w0; acc[j][1]+=hv*w1; acc[j][2]+=hv*w2; acc[j][3]+=hv*w3;
      }
    }
    __syncthreads();
    #pragma unroll
    for (int j=0;j<4;j++){
      int e = eh*4+j;
      float ig = sigf(acc[j][0]);
      float fg = sigf(acc[j][1]);
      float gg = tanhf(acc[j][2]);
      float og = sigf(acc[j][3]);
      float c = fg*cs[e][u] + ig*gg;
      float h = og*tanhf(c);
      cs[e][u]=c; hs[e][u]=h;
      if (t == t_store) finals[(size_t)(e0+e)*512 + dir*256 + u] = h;
    }
    __syncthreads();
  }
}

__global__ void combine_init(const float* __restrict__ lf, const float* __restrict__ rf,
                             float* __restrict__ h0, float* __restrict__ c0,
                             float* __restrict__ h1, float* __restrict__ c1,
                             int* __restrict__ tok){
  int i = blockIdx.x*blockDim.x + threadIdx.x;
  if (i < BATCH*HG){
    float v = 0.5f*(lf[i]+rf[i]);
    h0[i]=v; h1[i]=v; c0[i]=0.f; c1[i]=0.f;
  }
  if (i < BATCH) tok[i]=0;
}

// decoder layer 0: grid (64 batch-groups, 8 unit-groups), block 256.
// Block = 16 elems x 64 units; thread = 1 unit, 4 elems, 4 gates (16 acc chains).
__global__ void dec_l0(const int* __restrict__ tok,
                       const float* __restrict__ egen0,
                       const float* __restrict__ whhT,
                       const float* __restrict__ hin,
                       float* __restrict__ hout,
                       float* __restrict__ cst){
  const int e0 = blockIdx.x * 16;
  const int u = blockIdx.y*64 + (threadIdx.x & 63);
  const int er = threadIdx.x >> 6;   // 0..3, wave-uniform
  __shared__ float xs[16][512];
  for (int i=threadIdx.x; i<16*512; i+=256)
    ((float*)xs)[i] = hin[(size_t)e0*512 + i];
  __syncthreads();
  float acc[4][4];
  #pragma unroll
  for (int j=0;j<4;j++){
    int el = er*4 + j;
    int tk = tok[e0+el];
    const float* ep = egen0 + (size_t)tk*2048 + u;
    acc[j][0]=ep[0]; acc[j][1]=ep[512]; acc[j][2]=ep[1024]; acc[j][3]=ep[1536];
  }
  for (int k=0;k<512;k++){
    const float* w = whhT + (size_t)k*2048 + u;
    float w0=w[0], w1=w[512], w2=w[1024], w3=w[1536];
    #pragma unroll
    for (int j=0;j<4;j++){
      float hv = xs[er*4+j][k];
      acc[j][0]+=hv*w0; acc[j][1]+=hv*w1; acc[j][2]+=hv*w2; acc[j][3]+=hv*w3;
    }
  }
  #pragma unroll
  for (int j=0;j<4;j++){
    int e = e0 + er*4 + j;
    size_t idx = (size_t)e*512 + u;
    float ig = sigf(acc[j][0]);
    float fg = sigf(acc[j][1]);
    float gg = tanhf(acc[j][2]);
    float og = sigf(acc[j][3]);
    float c = fg*cst[idx] + ig*gg;
    float h = og*tanhf(c);
    cst[idx]=c; hout[idx]=h;
  }
}

// decoder layer 1: z = b + [x;h_prev] @ g1W (g1W = [WihT;WhhT], 1024x2048)
__global__ void dec_l1(const float* __restrict__ x,
                       const float* __restrict__ g1W,
                       const float* __restrict__ bias,
                       const float* __restrict__ hin,
                       float* __restrict__ hout,
                       float* __restrict__ cst){
  const int e0 = blockIdx.x * 16;
  const int u = blockIdx.y*64 + (threadIdx.x & 63);
  const int er = threadIdx.x >> 6;
  __shared__ float xh[16][1024];
  for (int i=threadIdx.x; i<16*512; i+=256){
    int e = i >> 9, k = i & 511;
    xh[e][k]       = x[(size_t)e0*512 + i];
    xh[e][512 + k] = hin[(size_t)e0*512 + i];
  }
  __syncthreads();
  float acc[4][4];
  const float b0=bias[u], b1=bias[512+u], b2=bias[1024+u], b3=bias[1536+u];
  #pragma unroll
  for (int j=0;j<4;j++){ acc[j][0]=b0; acc[j][1]=b1; acc[j][2]=b2; acc[j][3]=b3; }
  for (int k=0;k<1024;k++){
    const float* w = g1W + (size_t)k*2048 + u;
    float w0=w[0], w1=w[512], w2=w[1024], w3=w[1536];
    #pragma unroll
    for (int j=0;j<4;j++){
      float hv = xh[er*4+j][k];
      acc[j][0]+=hv*w0; acc[j][1]+=hv*w1; acc[j][2]+=hv*w2; acc[j][3]+=hv*w3;
    }
  }
  #pragma unroll
  for (int j=0;j<4;j++){
    int e = e0 + er*4 + j;
    size_t idx = (size_t)e*512 + u;
    float ig=sigf(acc[j][0]), fg=sigf(acc[j][1]);
    float gg=tanhf(acc[j][2]), og=sigf(acc[j][3]);
    float c = fg*cst[idx] + ig*gg;
    float h = og*tanhf(c);
    cst[idx]=c; hout[idx]=h;
  }
}

// logits + argmax: one wave per batch elem (4 waves/block, 256 blocks)
__global__ void dec_out(const float* __restrict__ h1,
                        const float* __restrict__ outW,
                        const float* __restrict__ outb,
                        float* __restrict__ out,
                        int* __restrict__ tok, int t){
  const int lane = threadIdx.x & 63;
  const int e = blockIdx.x*4 + (threadIdx.x >> 6);
  const float* h = h1 + (size_t)e*512;
  float s0=0,s1=0,s2=0,s3=0,s4=0;
  for (int k=lane;k<512;k+=64){
    float hv = h[k];
    s0 += hv*outW[k];
    s1 += hv*outW[512+k];
    s2 += hv*outW[1024+k];
    s3 += hv*outW[1536+k];
    s4 += hv*outW[2048+k];
  }
  #pragma unroll
  for (int off=32; off>0; off>>=1){
    s0 += __shfl_down(s0, off);
    s1 += __shfl_down(s1, off);
    s2 += __shfl_down(s2, off);
    s3 += __shfl_down(s3, off);
    s4 += __shfl_down(s4, off);
  }
  if (lane==0){
    float l[5] = { s0+outb[0], s1+outb[1], s2+outb[2], s3+outb[3], s4+outb[4] };
    float* op = out + ((size_t)e*TDEC + t)*5;
    float best = l[0]; int bi = 0;
    op[0] = l[0];
    #pragma unroll
    for (int v=1;v<5;v++){
      op[v] = l[v];
      if (l[v] > best){ best = l[v]; bi = v; }  // first-max, matches jnp.argmax
    }
    tok[e] = bi;
  }
}

extern "C" void kernel_launch(void* const* d_in, const int* in_sizes, int n_in,
                              void* d_out, int out_size, void* d_ws, size_t ws_size,
                              hipStream_t stream){
  (void)in_sizes; (void)n_in; (void)out_size;
  const int*   leftc    = (const int*)d_in[0];
  const int*   rightc   = (const int*)d_in[1];
  // d_in[2] = target_length (fixed 256 by setup_inputs; hardcoded as TDEC)
  const float* emb      = (const float*)d_in[3];
  const float* ctx0_Wih = (const float*)d_in[4];
  const float* ctx0_Whh = (const float*)d_in[5];
  const float* ctx0_b   = (const float*)d_in[6];
  const float* ctx1_Wih = (const float*)d_in[7];
  const float* ctx1_Whh = (const float*)d_in[8];
  const float* ctx1_b   = (const float*)d_in[9];
  const float* gen0_Wih = (const float*)d_in[10];
  const float* gen0_Whh = (const float*)d_in[11];
  const float* gen0_b   = (const float*)d_in[12];
  const float* gen1_Wih = (const float*)d_in[13];
  const float* gen1_Whh = (const float*)d_in[14];
  const float* gen1_b   = (const float*)d_in[15];
  const float* out_W    = (const float*)d_in[16];
  const float* out_b    = (const float*)d_in[17];
  float* out = (float*)d_out;

  char* p = (char*)d_ws;
  auto carve = [&](size_t nfloats)->float*{
    float* r = (float*)p;
    p += ((nfloats*sizeof(float) + 255) & ~(size_t)255);
    return r;
  };
  float* c0WhhT = carve((size_t)2*256*1024);
  float* c1WihT = carve((size_t)2*512*1024);
  float* c1WhhT = carve((size_t)2*256*1024);
  float* g0WhhT = carve((size_t)512*2048);
  float* g1W    = carve((size_t)1024*2048);   // [WihT; WhhT] stacked over k
  float* ectx0  = carve(2*5*1024);
  float* egen0  = carve(5*2048);
  float* leftF  = carve((size_t)BATCH*HG);
  float* rightF = carve((size_t)BATCH*HG);
  float* h0a    = carve((size_t)BATCH*HG);
  float* h0b    = carve((size_t)BATCH*HG);
  float* h1a    = carve((size_t)BATCH*HG);
  float* h1b    = carve((size_t)BATCH*HG);
  float* c0s    = carve((size_t)BATCH*HG);
  float* c1s    = carve((size_t)BATCH*HG);
  int*   tok    = (int*)carve(BATCH);
  float* y0     = carve((size_t)L_SEQ*BATCH*512);   // 210 MB, largest last
  if ((size_t)(p - (char*)d_ws) > ws_size) return;  // insufficient workspace -> loud fail

  auto T = [&](const float* s, float* d, int J, int K){
    int n = J*K;
    transpose_k<<<(n+255)/256, 256, 0, stream>>>(s, d, J, K);
  };
  T(ctx0_Whh,          c0WhhT,          1024, 256);
  T(ctx0_Whh+1024*256, c0WhhT+256*1024, 1024, 256);
  T(ctx1_Wih,          c1WihT,          1024, 512);
  T(ctx1_Wih+1024*512, c1WihT+512*1024, 1024, 512);
  T(ctx1_Whh,          c1WhhT,          1024, 256);
  T(ctx1_Whh+1024*256, c1WhhT+256*1024, 1024, 256);
  T(gen0_Whh, g0WhhT, 2048, 512);
  T(gen1_Wih, g1W,                    2048, 512);
  T(gen1_Whh, g1W + (size_t)512*2048, 2048, 512);
  embprep<<<(20480+255)/256, 256, 0, stream>>>(emb, ctx0_Wih, ctx0_b,
                                               gen0_Wih, gen0_b, ectx0, egen0);

  // left encode (finals at original t=99), then right (finals at t=0); y0 reused
  ctx_l0<<<dim3(128,2), 512, 0, stream>>>(leftc, ectx0, c0WhhT, y0);
  ctx_l1<<<dim3(128,2), 512, 0, stream>>>(y0, c1WihT, c1WhhT, ctx1_b, leftF, L_SEQ-1);
  ctx_l0<<<dim3(128,2), 512, 0, stream>>>(rightc, ectx0, c0WhhT, y0);
  ctx_l1<<<dim3(128,2), 512, 0, stream>>>(y0, c1WihT, c1WhhT, ctx1_b, rightF, 0);

  combine_init<<<(BATCH*HG+255)/256, 256, 0, stream>>>(leftF, rightF,
                                                       h0a, c0s, h1a, c1s, tok);

  for (int t=0;t<TDEC;t++){
    float* h0in  = (t&1)? h0b : h0a;
    float* h0out = (t&1)? h0a : h0b;
    float* h1in  = (t&1)? h1b : h1a;
    float* h1out = (t&1)? h1a : h1b;
    dec_l0<<<dim3(64,8), 256, 0, stream>>>(tok, egen0, g0WhhT, h0in, h0out, c0s);
    dec_l1<<<dim3(64,8), 256, 0, stream>>>(h0out, g1W, gen1_b, h1in, h1out, c1s);
    dec_out<<<256, 256, 0, stream>>>(h1out, out_W, out_b, out, tok, t);
  }
}